// Round 2
// baseline (891.543 us; speedup 1.0000x reference)
//
#include <hip/hip_runtime.h>
#include <hip/hip_bf16.h>

#define N_    8
#define H_    32
#define W_    32
#define C_    32
#define FH_   3
#define FW_   3
#define COUT_ 64
#define HO_   30
#define WO_   30
#define P_    (FH_ * FW_ * C_)          // 288
#define TILE_W 4
#define TW_COLS (TILE_W + FW_ - 1)      // 6
#define NTILES ((WO_ + TILE_W - 1) / TILE_W)  // 8

// Transpose k1,k2 from [P][COUT] to [COUT][P] so the main kernel can do
// float4 loads along p per lane (lane = co).
__global__ void kt_kernel(const float* __restrict__ k1,
                          const float* __restrict__ k2,
                          float* __restrict__ k1t,
                          float* __restrict__ k2t) {
    int idx = blockIdx.x * 256 + threadIdx.x;
    if (idx < P_ * COUT_) {
        int p  = idx >> 6;        // / COUT_
        int co = idx & (COUT_ - 1);
        k1t[co * P_ + p] = k1[idx];
        k2t[co * P_ + p] = k2[idx];
    }
}

template <bool TRANS>
__global__ __launch_bounds__(256, 4)
void bmorph_kernel(const float* __restrict__ x,
                   const float* __restrict__ k1,   // TRANS ? [COUT][P] : [P][COUT]
                   const float* __restrict__ k2,
                   const float* __restrict__ bias,
                   float* __restrict__ out) {
    __shared__ float lp1[FH_ * TW_COLS * C_];   // 576 floats
    __shared__ float lp2[FH_ * TW_COLS * C_];

    int b    = blockIdx.x;
    int tile = b % NTILES;
    int ho   = (b / NTILES) % HO_;
    int n    = b / (NTILES * HO_);
    int wo0  = tile * TILE_W;

    // ---- stage log-domain patch values for this block's x tile ----
    const int TOT = FH_ * TW_COLS * C_;         // 576
    for (int idx = threadIdx.x; idx < TOT; idx += 256) {
        int c = idx & (C_ - 1);
        int w = (idx >> 5) % TW_COLS;
        int r = idx / (TW_COLS * C_);
        int col = wo0 + w;
        if (col > W_ - 1) col = W_ - 1;         // clamp; clamped slots unused by valid wo
        float v = x[((n * H_ + (ho + r)) * W_ + col) * C_ + c];
        lp1[idx] = __logf(fmaxf(v, 0.1f));
        lp2[idx] = __logf(fmaxf(-v, 0.1f));
    }
    __syncthreads();

    int t  = threadIdx.x >> 6;      // wave id -> which wo in the tile
    int co = threadIdx.x & 63;      // lane    -> output channel

    float m11 = -3.0e38f, m12 = -3.0e38f, m21 = -3.0e38f, m22 = -3.0e38f;

    const float* k1p = TRANS ? (k1 + co * P_) : (k1 + co);
    const float* k2p = TRANS ? (k2 + co * P_) : (k2 + co);

    #pragma unroll
    for (int i = 0; i < FH_; ++i) {
        #pragma unroll
        for (int j = 0; j < FW_; ++j) {
            const float* l1 = &lp1[(i * TW_COLS + t + j) * C_];
            const float* l2 = &lp2[(i * TW_COLS + t + j) * C_];
            const int pbase = (i * FW_ + j) * C_;
            #pragma unroll
            for (int c4 = 0; c4 < C_ / 4; ++c4) {
                float4 a1 = *reinterpret_cast<const float4*>(l1 + c4 * 4);
                float4 a2 = *reinterpret_cast<const float4*>(l2 + c4 * 4);
                float4 kv1, kv2;
                if (TRANS) {
                    kv1 = *reinterpret_cast<const float4*>(k1p + pbase + c4 * 4);
                    kv2 = *reinterpret_cast<const float4*>(k2p + pbase + c4 * 4);
                } else {
                    kv1.x = k1p[(pbase + c4 * 4 + 0) * COUT_];
                    kv1.y = k1p[(pbase + c4 * 4 + 1) * COUT_];
                    kv1.z = k1p[(pbase + c4 * 4 + 2) * COUT_];
                    kv1.w = k1p[(pbase + c4 * 4 + 3) * COUT_];
                    kv2.x = k2p[(pbase + c4 * 4 + 0) * COUT_];
                    kv2.y = k2p[(pbase + c4 * 4 + 1) * COUT_];
                    kv2.z = k2p[(pbase + c4 * 4 + 2) * COUT_];
                    kv2.w = k2p[(pbase + c4 * 4 + 3) * COUT_];
                }
                m11 = fmaxf(m11, a1.x + kv1.x);
                m11 = fmaxf(m11, a1.y + kv1.y);
                m11 = fmaxf(m11, a1.z + kv1.z);
                m11 = fmaxf(m11, a1.w + kv1.w);
                m12 = fmaxf(m12, a1.x + kv2.x);
                m12 = fmaxf(m12, a1.y + kv2.y);
                m12 = fmaxf(m12, a1.z + kv2.z);
                m12 = fmaxf(m12, a1.w + kv2.w);
                m21 = fmaxf(m21, a2.x + kv1.x);
                m21 = fmaxf(m21, a2.y + kv1.y);
                m21 = fmaxf(m21, a2.z + kv1.z);
                m21 = fmaxf(m21, a2.w + kv1.w);
                m22 = fmaxf(m22, a2.x + kv2.x);
                m22 = fmaxf(m22, a2.y + kv2.y);
                m22 = fmaxf(m22, a2.z + kv2.z);
                m22 = fmaxf(m22, a2.w + kv2.w);
            }
        }
    }

    int wo = wo0 + t;
    if (wo < WO_) {
        float r = __expf(m11) - __expf(m12) - __expf(m21) + __expf(m22) + bias[co];
        out[((n * HO_ + ho) * WO_ + wo) * COUT_ + co] = r;
    }
}

extern "C" void kernel_launch(void* const* d_in, const int* in_sizes, int n_in,
                              void* d_out, int out_size, void* d_ws, size_t ws_size,
                              hipStream_t stream) {
    const float* x    = (const float*)d_in[0];
    const float* k1   = (const float*)d_in[1];
    const float* k2   = (const float*)d_in[2];
    const float* bias = (const float*)d_in[3];
    float* out = (float*)d_out;

    const size_t kt_bytes = (size_t)P_ * COUT_ * sizeof(float);   // 73728 each
    const int nblocks = N_ * HO_ * NTILES;                        // 1920

    if (ws_size >= 2 * kt_bytes) {
        float* k1t = (float*)d_ws;
        float* k2t = (float*)((char*)d_ws + kt_bytes);
        kt_kernel<<<(P_ * COUT_ + 255) / 256, 256, 0, stream>>>(k1, k2, k1t, k2t);
        bmorph_kernel<true><<<nblocks, 256, 0, stream>>>(x, k1t, k2t, bias, out);
    } else {
        bmorph_kernel<false><<<nblocks, 256, 0, stream>>>(x, k1, k2, bias, out);
    }
}

// Round 3
// 102.949 us; speedup vs baseline: 8.6601x; 8.6601x over previous
//
#include <hip/hip_runtime.h>
#include <hip/hip_bf16.h>

#define N_    8
#define H_    32
#define W_    32
#define C_    32
#define FH_   3
#define FW_   3
#define COUT_ 64
#define HO_   30
#define WO_   30
#define P_    (FH_ * FW_ * C_)   // 288
#define WPW   8                  // wo pixels per wave
#define NCOL  (WPW + FW_ - 1)    // 10 columns of a-values per wave

// Transpose k1,k2 from [P][COUT] to [COUT][P] so each lane (lane = co) can
// float4-load 4 consecutive p values.
__global__ void kt_kernel(const float* __restrict__ k1,
                          const float* __restrict__ k2,
                          float* __restrict__ k1t,
                          float* __restrict__ k2t) {
    int idx = blockIdx.x * 256 + threadIdx.x;
    if (idx < P_ * COUT_) {
        int p  = idx >> 6;        // / COUT_
        int co = idx & (COUT_ - 1);
        k1t[co * P_ + p] = k1[idx];
        k2t[co * P_ + p] = k2[idx];
    }
}

// Block = (n, ho): 4 waves, wave w computes wo = 8w..8w+7 (last wave: 6 valid),
// all 64 output channels (lane = co). 32 accumulators/lane.
// Outer loops unroll(1) to bound the live set and prevent the round-2 spill.
template <bool TRANS>
__global__ __launch_bounds__(256, 2)
void bmorph_kernel(const float* __restrict__ x,
                   const float* __restrict__ k1,   // TRANS ? [COUT][P] : [P][COUT]
                   const float* __restrict__ k2,
                   const float* __restrict__ bias,
                   float* __restrict__ out) {
    __shared__ float lp1[FH_ * W_ * C_];   // 3072 floats = 12 KB
    __shared__ float lp2[FH_ * W_ * C_];

    const int b  = blockIdx.x;
    const int ho = b % HO_;
    const int n  = b / HO_;

    // ---- stage rows ho..ho+2, all 32 cols: contiguous 3072-float slab ----
    const float* xs = x + (size_t)(n * H_ + ho) * (W_ * C_);
    #pragma unroll
    for (int it = 0; it < 3; ++it) {
        int idx4 = threadIdx.x + it * 256;           // 0..767 float4 slots
        float4 v = *reinterpret_cast<const float4*>(xs + idx4 * 4);
        float4 l1, l2;
        l1.x = __logf(fmaxf(v.x, 0.1f));  l2.x = __logf(fmaxf(-v.x, 0.1f));
        l1.y = __logf(fmaxf(v.y, 0.1f));  l2.y = __logf(fmaxf(-v.y, 0.1f));
        l1.z = __logf(fmaxf(v.z, 0.1f));  l2.z = __logf(fmaxf(-v.z, 0.1f));
        l1.w = __logf(fmaxf(v.w, 0.1f));  l2.w = __logf(fmaxf(-v.w, 0.1f));
        *reinterpret_cast<float4*>(lp1 + idx4 * 4) = l1;
        *reinterpret_cast<float4*>(lp2 + idx4 * 4) = l2;
    }
    __syncthreads();

    const int w   = threadIdx.x >> 6;   // wave -> wo strip
    const int co  = threadIdx.x & 63;   // lane -> output channel
    const int wo0 = w * WPW;

    float m11[WPW], m12[WPW], m21[WPW], m22[WPW];
    #pragma unroll
    for (int p = 0; p < WPW; ++p) {
        m11[p] = -3.0e38f; m12[p] = -3.0e38f; m21[p] = -3.0e38f; m22[p] = -3.0e38f;
    }

    const float* k1p = TRANS ? (k1 + co * P_) : (k1 + co);
    const float* k2p = TRANS ? (k2 + co * P_) : (k2 + co);

    // columns this wave needs (clamped; clamped slots feed only invalid pixels)
    int colq[NCOL];
    #pragma unroll
    for (int q = 0; q < NCOL; ++q) {
        int col = wo0 + q;
        colq[q] = (col > W_ - 1) ? (W_ - 1) : col;
    }

    #pragma unroll 1
    for (int i = 0; i < FH_; ++i) {
        #pragma unroll 1
        for (int c4 = 0; c4 < C_ / 4; ++c4) {
            // hold the 10 columns of a-values (both polarities) in registers;
            // these are wave-uniform LDS broadcasts (conflict-free).
            float4 a1r[NCOL], a2r[NCOL];
            #pragma unroll
            for (int q = 0; q < NCOL; ++q) {
                int off = (i * W_ + colq[q]) * C_ + c4 * 4;
                a1r[q] = *reinterpret_cast<const float4*>(lp1 + off);
                a2r[q] = *reinterpret_cast<const float4*>(lp2 + off);
            }
            #pragma unroll
            for (int j = 0; j < FW_; ++j) {
                const int pb = (i * FW_ + j) * C_ + c4 * 4;
                float4 kv1, kv2;
                if (TRANS) {
                    kv1 = *reinterpret_cast<const float4*>(k1p + pb);
                    kv2 = *reinterpret_cast<const float4*>(k2p + pb);
                } else {
                    kv1.x = k1p[(pb + 0) * COUT_]; kv1.y = k1p[(pb + 1) * COUT_];
                    kv1.z = k1p[(pb + 2) * COUT_]; kv1.w = k1p[(pb + 3) * COUT_];
                    kv2.x = k2p[(pb + 0) * COUT_]; kv2.y = k2p[(pb + 1) * COUT_];
                    kv2.z = k2p[(pb + 2) * COUT_]; kv2.w = k2p[(pb + 3) * COUT_];
                }
                #pragma unroll
                for (int p = 0; p < WPW; ++p) {
                    float4 a1 = a1r[p + j];
                    float4 a2 = a2r[p + j];
                    // nested fmaxf pairs -> v_max3_f32 fusion opportunity
                    m11[p] = fmaxf(fmaxf(m11[p], a1.x + kv1.x), a1.y + kv1.y);
                    m11[p] = fmaxf(fmaxf(m11[p], a1.z + kv1.z), a1.w + kv1.w);
                    m12[p] = fmaxf(fmaxf(m12[p], a1.x + kv2.x), a1.y + kv2.y);
                    m12[p] = fmaxf(fmaxf(m12[p], a1.z + kv2.z), a1.w + kv2.w);
                    m21[p] = fmaxf(fmaxf(m21[p], a2.x + kv1.x), a2.y + kv1.y);
                    m21[p] = fmaxf(fmaxf(m21[p], a2.z + kv1.z), a2.w + kv1.w);
                    m22[p] = fmaxf(fmaxf(m22[p], a2.x + kv2.x), a2.y + kv2.y);
                    m22[p] = fmaxf(fmaxf(m22[p], a2.z + kv2.z), a2.w + kv2.w);
                }
            }
        }
    }

    const float bz = bias[co];
    #pragma unroll
    for (int p = 0; p < WPW; ++p) {
        int wo = wo0 + p;
        if (wo < WO_) {
            float r = __expf(m11[p]) - __expf(m12[p])
                    - __expf(m21[p]) + __expf(m22[p]) + bz;
            out[((size_t)(n * HO_ + ho) * WO_ + wo) * COUT_ + co] = r;
        }
    }
}

extern "C" void kernel_launch(void* const* d_in, const int* in_sizes, int n_in,
                              void* d_out, int out_size, void* d_ws, size_t ws_size,
                              hipStream_t stream) {
    const float* x    = (const float*)d_in[0];
    const float* k1   = (const float*)d_in[1];
    const float* k2   = (const float*)d_in[2];
    const float* bias = (const float*)d_in[3];
    float* out = (float*)d_out;

    const size_t kt_bytes = (size_t)P_ * COUT_ * sizeof(float);   // 73728 each
    const int nblocks = N_ * HO_;                                 // 240

    if (ws_size >= 2 * kt_bytes) {
        float* k1t = (float*)d_ws;
        float* k2t = (float*)((char*)d_ws + kt_bytes);
        kt_kernel<<<(P_ * COUT_ + 255) / 256, 256, 0, stream>>>(k1, k2, k1t, k2t);
        bmorph_kernel<true><<<nblocks, 256, 0, stream>>>(x, k1t, k2t, bias, out);
    } else {
        bmorph_kernel<false><<<nblocks, 256, 0, stream>>>(x, k1, k2, bias, out);
    }
}

// Round 4
// 84.504 us; speedup vs baseline: 10.5503x; 1.2183x over previous
//
#include <hip/hip_runtime.h>
#include <hip/hip_bf16.h>

#define N_    8
#define H_    32
#define W_    32
#define C_    32
#define FH_   3
#define FW_   3
#define COUT_ 64
#define HO_   30
#define WO_   30
#define P_    (FH_ * FW_ * C_)   // 288
#define WPW   4                  // wo pixels per wave
#define NCOL  (WPW + FW_ - 1)    // 6 columns of a-values per wave
#define NITER (FH_ * (C_ / 4))   // 24 flat (i,c4) iterations

// guaranteed 3-input max (clang doesn't always fuse nested fmaxf)
__device__ __forceinline__ float max3f(float a, float b, float c) {
    float d;
    asm("v_max3_f32 %0, %1, %2, %3" : "=v"(d) : "v"(a), "v"(b), "v"(c));
    return d;
}

// load the 12 k-floats (3 j * 4 elems) for each kernel at flat iter it_
// k layout is the original [P][COUT]: k[pp*64+co] is a coalesced dword load.
#define LOADKV(buf1, buf2, it_) do {                                        \
    const int i_ = (it_) >> 3, c4_ = (it_) & 7;                             \
    _Pragma("unroll")                                                       \
    for (int j = 0; j < FW_; ++j) {                                         \
        _Pragma("unroll")                                                   \
        for (int e = 0; e < 4; ++e) {                                       \
            const int pp = (i_ * FW_ + j) * C_ + c4_ * 4 + e;               \
            buf1[j * 4 + e] = kb1[(size_t)pp * COUT_];                      \
            buf2[j * 4 + e] = kb2[(size_t)pp * COUT_];                      \
        }                                                                   \
    }                                                                       \
} while (0)

// one flat iteration of the max-plus accumulation using kv buffers buf1/buf2
#define COMPUTE(buf1, buf2, it_) do {                                       \
    const int i_ = (it_) >> 3, c4_ = (it_) & 7;                             \
    float4 a1r[NCOL], a2r[NCOL];                                            \
    _Pragma("unroll")                                                       \
    for (int q = 0; q < NCOL; ++q) {                                        \
        int col = wo0 + q; if (col > W_ - 1) col = W_ - 1;                  \
        const int off = (i_ * W_ + col) * C_ + c4_ * 4;                     \
        a1r[q] = *reinterpret_cast<const float4*>(lp1 + off);               \
        a2r[q] = *reinterpret_cast<const float4*>(lp2 + off);               \
    }                                                                       \
    _Pragma("unroll")                                                       \
    for (int j = 0; j < FW_; ++j) {                                         \
        _Pragma("unroll")                                                   \
        for (int p = 0; p < WPW; ++p) {                                     \
            const float4 a1 = a1r[p + j];                                   \
            const float4 a2 = a2r[p + j];                                   \
            m11[p] = max3f(m11[p], a1.x + buf1[j*4+0], a1.y + buf1[j*4+1]); \
            m11[p] = max3f(m11[p], a1.z + buf1[j*4+2], a1.w + buf1[j*4+3]); \
            m12[p] = max3f(m12[p], a1.x + buf2[j*4+0], a1.y + buf2[j*4+1]); \
            m12[p] = max3f(m12[p], a1.z + buf2[j*4+2], a1.w + buf2[j*4+3]); \
            m21[p] = max3f(m21[p], a2.x + buf1[j*4+0], a2.y + buf1[j*4+1]); \
            m21[p] = max3f(m21[p], a2.z + buf1[j*4+2], a2.w + buf1[j*4+3]); \
            m22[p] = max3f(m22[p], a2.x + buf2[j*4+0], a2.y + buf2[j*4+1]); \
            m22[p] = max3f(m22[p], a2.z + buf2[j*4+2], a2.w + buf2[j*4+3]); \
        }                                                                   \
    }                                                                       \
} while (0)

// Block = (n, ho, strip): 4 waves, wave w computes wo = strip*16 + w*4 .. +3,
// all 64 output channels (lane = co). 16 accumulators/lane.
// 480 blocks -> ~2 blocks/CU -> 2 waves/SIMD for latency hiding.
__global__ __launch_bounds__(256, 2)
void bmorph_kernel(const float* __restrict__ x,
                   const float* __restrict__ k1,   // [P][COUT]
                   const float* __restrict__ k2,
                   const float* __restrict__ bias,
                   float* __restrict__ out) {
    __shared__ float lp1[FH_ * W_ * C_];   // 3072 floats = 12 KB
    __shared__ float lp2[FH_ * W_ * C_];

    const int b     = blockIdx.x;
    const int strip = b & 1;
    const int ho    = (b >> 1) % HO_;
    const int n     = b / (2 * HO_);

    // ---- stage rows ho..ho+2 (contiguous 3072-float slab) in log domain ----
    const float* xs = x + (size_t)(n * H_ + ho) * (W_ * C_);
    #pragma unroll
    for (int it = 0; it < 3; ++it) {
        const int idx4 = threadIdx.x + it * 256;     // 0..767 float4 slots
        float4 v = *reinterpret_cast<const float4*>(xs + idx4 * 4);
        float4 l1, l2;
        l1.x = __logf(fmaxf(v.x, 0.1f));  l2.x = __logf(fmaxf(-v.x, 0.1f));
        l1.y = __logf(fmaxf(v.y, 0.1f));  l2.y = __logf(fmaxf(-v.y, 0.1f));
        l1.z = __logf(fmaxf(v.z, 0.1f));  l2.z = __logf(fmaxf(-v.z, 0.1f));
        l1.w = __logf(fmaxf(v.w, 0.1f));  l2.w = __logf(fmaxf(-v.w, 0.1f));
        *reinterpret_cast<float4*>(lp1 + idx4 * 4) = l1;
        *reinterpret_cast<float4*>(lp2 + idx4 * 4) = l2;
    }
    __syncthreads();

    const int w   = threadIdx.x >> 6;   // wave -> wo sub-strip
    const int co  = threadIdx.x & 63;   // lane -> output channel
    const int wo0 = strip * 16 + w * WPW;

    float m11[WPW], m12[WPW], m21[WPW], m22[WPW];
    #pragma unroll
    for (int p = 0; p < WPW; ++p) {
        m11[p] = -3.0e38f; m12[p] = -3.0e38f; m21[p] = -3.0e38f; m22[p] = -3.0e38f;
    }

    const float* kb1 = k1 + co;
    const float* kb2 = k2 + co;

    // ---- software-pipelined main loop: prefetch kv for it+1 while computing it
    float kvA1[12], kvA2[12], kvB1[12], kvB2[12];
    LOADKV(kvA1, kvA2, 0);
    #pragma unroll 1
    for (int it = 0; it < NITER; it += 2) {
        LOADKV(kvB1, kvB2, it + 1);
        COMPUTE(kvA1, kvA2, it);
        const int nx = (it + 2 < NITER) ? it + 2 : 0;   // clamped dummy at tail
        LOADKV(kvA1, kvA2, nx);
        COMPUTE(kvB1, kvB2, it + 1);
    }

    const float bz = bias[co];
    #pragma unroll
    for (int p = 0; p < WPW; ++p) {
        const int wo = wo0 + p;
        if (wo < WO_) {
            float r = __expf(m11[p]) - __expf(m12[p])
                    - __expf(m21[p]) + __expf(m22[p]) + bz;
            out[((size_t)(n * HO_ + ho) * WO_ + wo) * COUT_ + co] = r;
        }
    }
}

extern "C" void kernel_launch(void* const* d_in, const int* in_sizes, int n_in,
                              void* d_out, int out_size, void* d_ws, size_t ws_size,
                              hipStream_t stream) {
    const float* x    = (const float*)d_in[0];
    const float* k1   = (const float*)d_in[1];
    const float* k2   = (const float*)d_in[2];
    const float* bias = (const float*)d_in[3];
    float* out = (float*)d_out;

    const int nblocks = N_ * HO_ * 2;   // 480
    bmorph_kernel<<<nblocks, 256, 0, stream>>>(x, k1, k2, bias, out);
}